// Round 7
// baseline (256.525 us; speedup 1.0000x reference)
//
#include <hip/hip_runtime.h>

#define T_TERMS 768
#define NV 6
#define D1 5
#define D2 9
#define T2 (T_TERMS * T_TERMS)                 // 589824
#define PTOT (T2 + T_TERMS + 1)                // 590593
#define NROWS ((unsigned int)PTOT * NV)        // 3,543,558 rows per tensor
#define NOUT (NROWS * (unsigned int)D2)        // 31,892,022 f32 per tensor (== 2 mod 4)
#define SQ_BLOCKS 4608u                        // 768 t-values x 6 s-chunks of 128
#define TAIL_ROW0 ((unsigned int)T2 * NV)      // 3,538,944
#define TAIL_BLOCKS 7u
#define GRID_X (SQ_BLOCKS + TAIL_BLOCKS)       // 4615
#define BLK_DWORDS (768u * D2)                 // 6912 dwords out per block

typedef float f4 __attribute__((ext_vector_type(4)));
typedef float f2 __attribute__((ext_vector_type(2)));

// Kernel 1: l (sum of per-term interval lows of under) + u (sum of highs of
// over) + relu relaxation coefs, one block of 768 threads.
__global__ void bounds_coef_kernel(const float* __restrict__ Pu,
                                   const float* __restrict__ Po,
                                   float* __restrict__ ws) {
    int t = threadIdx.x;
    float tlo = 0.f, thi = 0.f;
    if (t < T_TERMS) {
        f2 r[15];
        const f2* p2 = (const f2*)(Pu + t * (NV * D1));
        #pragma unroll
        for (int i = 0; i < 15; ++i) r[i] = p2[i];
        const float* rf = (const float*)r;
        float clo = 1.f, chi = 1.f;
        #pragma unroll
        for (int v = 0; v < NV; ++v) {
            float lo = rf[v * 5 + 0], hi = lo;
            #pragma unroll
            for (int i = 1; i < 5; ++i) {
                float x = rf[v * 5 + i];
                lo = fminf(lo, x); hi = fmaxf(hi, x);
            }
            float a = clo * lo, b = clo * hi, c = chi * lo, d = chi * hi;
            clo = fminf(fminf(a, b), fminf(c, d));
            chi = fmaxf(fmaxf(a, b), fmaxf(c, d));
        }
        tlo = clo;
        const f2* q2 = (const f2*)(Po + t * (NV * D1));
        #pragma unroll
        for (int i = 0; i < 15; ++i) r[i] = q2[i];
        clo = 1.f; chi = 1.f;
        #pragma unroll
        for (int v = 0; v < NV; ++v) {
            float lo = rf[v * 5 + 0], hi = lo;
            #pragma unroll
            for (int i = 1; i < 5; ++i) {
                float x = rf[v * 5 + i];
                lo = fminf(lo, x); hi = fmaxf(hi, x);
            }
            float a = clo * lo, b = clo * hi, c = chi * lo, d = chi * hi;
            clo = fminf(fminf(a, b), fminf(c, d));
            chi = fmaxf(fmaxf(a, b), fmaxf(c, d));
        }
        thi = chi;
    }
    __shared__ float slo[12], shi[12];
    for (int off = 32; off; off >>= 1) {
        tlo += __shfl_down(tlo, off);
        thi += __shfl_down(thi, off);
    }
    int wave = threadIdx.x >> 6;
    if ((threadIdx.x & 63) == 0) { slo[wave] = tlo; shi[wave] = thi; }
    __syncthreads();
    if (threadIdx.x == 0) {
        float l = 0.f, u = 0.f;
        #pragma unroll
        for (int w = 0; w < 12; ++w) { l += slo[w]; u += shi[w]; }
        float den = (u - l > 0.f) ? (u - l) : 1.f;
        float au, bu, cu, ao, bo, co;
        if (l >= 0.f) {
            au = 0.f; bu = 1.f; cu = 0.f;
            ao = 0.f; bo = 1.f; co = 0.f;
        } else if (u <= 0.f) {
            au = bu = cu = 0.f;
            ao = bo = co = 0.f;
        } else {
            au = 1.f / den; bu = -l / den; cu = 0.f;
            float d2 = den * den;
            ao = u / d2; bo = -2.f * u * l / d2; co = u * l * l / d2;
        }
        ws[0] = au; ws[1] = bu; ws[2] = cu;
        ws[3] = ao; ws[4] = bo; ws[5] = co;
    }
}

// Kernel 2: sq blocks (bx < SQ_BLOCKS): t = bx/6, s-chunk = bx%6.
//   768 threads = 128 s x 6 v. B chunk (3840 dwords, contiguous) + A row
//   (30 dwords) staged to LDS with coalesced loads -> no per-lane gathers.
// tail blocks: lin (B=ones elevation) + const rows, row-per-thread.
// All blocks: c[9] -> LDS -> coalesced quad stores; out base = bx*6912 dwords.
__global__ __launch_bounds__(768) void expand_kernel(
        const float* __restrict__ Pu,
        const float* __restrict__ Po,
        const float* __restrict__ coef,
        float* __restrict__ out) {
    __shared__ float lds[BLK_DWORDS + 32];     // 0..6911 B-stage/out-stage, 6912+ A
    static constexpr float Wt[5][5] = {
        {1.0f,        4.0f/8.0f,   6.0f/28.0f,  4.0f/56.0f,  1.0f/70.0f},
        {4.0f/8.0f,   16.0f/28.0f, 24.0f/56.0f, 16.0f/70.0f, 4.0f/56.0f},
        {6.0f/28.0f,  24.0f/56.0f, 36.0f/70.0f, 24.0f/56.0f, 6.0f/28.0f},
        {4.0f/56.0f,  16.0f/70.0f, 24.0f/56.0f, 16.0f/28.0f, 4.0f/8.0f},
        {1.0f/70.0f,  4.0f/56.0f,  6.0f/28.0f,  4.0f/8.0f,   1.0f}
    };

    const unsigned tid = threadIdx.x;
    const unsigned bx = blockIdx.x;
    const unsigned ten = blockIdx.y;           // 0 = under, 1 = over
    const float* __restrict__ P = ten ? Po : Pu;
    const float sc_sq  = coef[ten * 3 + 0];
    const float sc_lin = coef[ten * 3 + 1];
    const float sc_con = coef[ten * 3 + 2];

    float c[9] = {0.f,0.f,0.f,0.f,0.f,0.f,0.f,0.f,0.f};
    bool fullstore = true;

    if (bx < SQ_BLOCKS) {
        const unsigned t = bx / 6u;
        const unsigned chunk = bx - t * 6u;
        const unsigned s0 = chunk * 128u;
        // stage B chunk: 3840 contiguous dwords, 5 coalesced passes
        const float* __restrict__ Bsrc = P + s0 * 30u;
        #pragma unroll
        for (unsigned kk = 0; kk < 5; ++kk)
            lds[tid + 768u * kk] = Bsrc[tid + 768u * kk];
        // stage A row block: 30 contiguous dwords
        if (tid < 30u) lds[BLK_DWORDS + tid] = P[t * 30u + tid];
        __syncthreads();

        const unsigned s_local = tid / 6u;
        const unsigned v = tid - s_local * 6u;
        float a[5], b[5];
        #pragma unroll
        for (int i = 0; i < 5; ++i) a[i] = lds[BLK_DWORDS + v * 5u + i];
        #pragma unroll
        for (int i = 0; i < 5; ++i) b[i] = lds[s_local * 30u + v * 5u + i];
        const float scale = (v == 0u) ? sc_sq : 1.f;
        #pragma unroll
        for (int i = 0; i < 5; ++i) a[i] *= scale;
        #pragma unroll
        for (int i = 0; i < 5; ++i)
            #pragma unroll
            for (int j = 0; j < 5; ++j)
                c[i + j] = fmaf(Wt[i][j] * a[i], b[j], c[i + j]);
        __syncthreads();   // all B/A reads done before out-stage overwrites
    } else {
        const unsigned rbase = TAIL_ROW0 + (bx - SQ_BLOCKS) * 768u;
        const unsigned r = rbase + tid;
        if (r < NROWS) {
            unsigned p = r / 6u;
            unsigned v = r - p * 6u;
            float a[5];
            float scale;
            if (p < (unsigned)(T2 + T_TERMS)) {
                unsigned t = p - (unsigned)T2;
                const float* A = P + (t * 6u + v) * 5u;
                #pragma unroll
                for (int i = 0; i < 5; ++i) a[i] = A[i];
                scale = (v == 0u) ? sc_lin : 1.f;
            } else {
                #pragma unroll
                for (int i = 0; i < 5; ++i) a[i] = 1.f;
                scale = (v == 0u) ? sc_con : 1.f;
            }
            #pragma unroll
            for (int i = 0; i < 5; ++i) a[i] *= scale;
            #pragma unroll
            for (int i = 0; i < 5; ++i)
                #pragma unroll
                for (int j = 0; j < 5; ++j)
                    c[i + j] = fmaf(Wt[i][j], a[i], c[i + j]);   // B = ones
        }
        fullstore = (rbase + 768u <= NROWS);
        __syncthreads();
    }

    #pragma unroll
    for (int k = 0; k < 9; ++k) lds[tid * 9u + k] = c[k];   // stride 9: 2-way, free
    __syncthreads();

    float* __restrict__ ob = out + (size_t)ten * NOUT + (size_t)bx * BLK_DWORDS;
    if (fullstore) {
        if (ten == 0u) {
            const f4* l4 = (const f4*)lds;
            f4* o4 = (f4*)ob;
            o4[tid]          = l4[tid];
            o4[tid + 768u]   = l4[tid + 768u];
            if (tid < 192u) o4[tid + 1536u] = l4[tid + 1536u];
        } else {
            // base ≡ 2 (mod 4) dwords: peel 2 head + 2 tail, 1727 aligned quads
            if (tid < 2u) ob[tid] = lds[tid];
            if (tid >= 2u && tid < 4u) ob[6908u + tid] = lds[6908u + tid];
            const f2* l2 = (const f2*)lds;
            {
                unsigned q = tid;
                f2 x = l2[1u + 2u * q], y = l2[2u + 2u * q];
                f4 vv; vv.x = x.x; vv.y = x.y; vv.z = y.x; vv.w = y.y;
                *(f4*)(ob + 2u + 4u * q) = vv;
            }
            {
                unsigned q = tid + 768u;
                f2 x = l2[1u + 2u * q], y = l2[2u + 2u * q];
                f4 vv; vv.x = x.x; vv.y = x.y; vv.z = y.x; vv.w = y.y;
                *(f4*)(ob + 2u + 4u * q) = vv;
            }
            if (tid < 191u) {
                unsigned q = tid + 1536u;
                f2 x = l2[1u + 2u * q], y = l2[2u + 2u * q];
                f4 vv; vv.x = x.x; vv.y = x.y; vv.z = y.x; vv.w = y.y;
                *(f4*)(ob + 2u + 4u * q) = vv;
            }
        }
    } else {
        const unsigned nd = (NROWS - (TAIL_ROW0 + (bx - SQ_BLOCKS) * 768u)) * 9u;
        for (unsigned x = tid; x < nd; x += 768u) ob[x] = lds[x];
    }
}

extern "C" void kernel_launch(void* const* d_in, const int* in_sizes, int n_in,
                              void* d_out, int out_size, void* d_ws, size_t ws_size,
                              hipStream_t stream) {
    const float* Pu = (const float*)d_in[0];
    const float* Po = (const float*)d_in[1];
    float* ws = (float*)d_ws;
    float* out = (float*)d_out;

    bounds_coef_kernel<<<1, 768, 0, stream>>>(Pu, Po, ws);

    dim3 grid(GRID_X, 2, 1);
    expand_kernel<<<grid, 768, 0, stream>>>(Pu, Po, ws, out);
}